// Round 1
// 563.816 us; speedup vs baseline: 1.4306x; 1.4306x over previous
//
#include <hip/hip_runtime.h>
#include <cmath>

#define TT   6
#define NB   128
#define DIM  192
#define SCALE 0.17677669529663687f

typedef __attribute__((ext_vector_type(8))) short v8s;
typedef __attribute__((ext_vector_type(4))) float v4f;

__device__ __forceinline__ short f2bf(float f) {
  union { float f; unsigned u; } v; v.f = f;
  unsigned r = v.u + 0x7fffu + ((v.u >> 16) & 1u);
  return (short)(r >> 16);
}
__device__ __forceinline__ void fence() {
  __asm__ volatile("s_waitcnt lgkmcnt(0)" ::: "memory");
}

// ---- fp32 -> bf16 weight converter ----
__global__ void cvt_kernel(const float* __restrict__ src, short* __restrict__ dst, int n4) {
  int idx = blockIdx.x * 256 + threadIdx.x;
  if (idx >= n4) return;
  const float* s = src + idx * 4;
  short4 r;
  r.x = f2bf(s[0]); r.y = f2bf(s[1]); r.z = f2bf(s[2]); r.w = f2bf(s[3]);
  *(short4*)(dst + idx * 4) = r;
}

// ---- sine position table: pos[64][192] f32 (identical formula to prior in-kernel table) ----
__global__ void pos_kernel(float* __restrict__ pos) {
  int idx = blockIdx.x * 256 + threadIdx.x;
  if (idx >= 64 * 192) return;
  int row = idx / 192, c = idx - row * 192;
  int e  = (c < 96) ? (row >> 3) : (row & 7);
  int cc = (c < 96) ? c : c - 96;
  int m = cc >> 1;
  float embed = (float)(e + 1) * (6.283185307179586f / 8.000001f);
  float dt = powf(10000.0f, (float)m * (1.0f / 48.0f));
  float ang = embed / dt;
  pos[idx] = (cc & 1) ? cosf(ang) : sinf(ang);
}

// ---- QKV pre-kernel: one block per (b,t). Q,K row-major [hw][ch]; V transposed [ch][hw].
// Math identical to the old in-loop staging+GEMM (bf16(x+pos), same mfma chains, SCALE on Q).
__global__ __launch_bounds__(256) void qkv_kernel(
    const float* __restrict__ x, const float* __restrict__ pos,
    const short* __restrict__ Wqkv_bf,
    short* __restrict__ Qb, short* __restrict__ Kb, short* __restrict__ Vtb) {
  __shared__ short XP[64 * 200];
  int bid = blockIdx.x;
  int t = bid % TT, b = bid / TT;
  int tid = threadIdx.x, w = tid >> 6, lane = tid & 63;
  int l15 = lane & 15, quad = lane >> 4;
  const float* xrow = x + (size_t)(b * (TT * 64) + t * 64) * DIM;
  for (int c = tid; c < 64 * 24; c += 256) {
    int row = c / 24, col8 = (c - (c / 24) * 24) * 8;
    const float* xs = xrow + row * DIM + col8;
    const float* pp = pos + row * DIM + col8;
    v8s r8;
#pragma unroll
    for (int jj = 0; jj < 8; jj++) r8[jj] = f2bf(xs[jj] + pp[jj]);
    *(v8s*)(XP + row * 200 + col8) = r8;
  }
  __syncthreads();
  const v4f vzero = {0.f, 0.f, 0.f, 0.f};
  size_t obase = (size_t)(b * TT + t) * 64 * DIM;
#pragma unroll
  for (int cti = 0; cti < 9; cti++) {
    int r0 = w * 144 + cti * 16;
    v4f acc[4] = {vzero, vzero, vzero, vzero};
#pragma unroll
    for (int ks = 0; ks < 6; ks++) {
      v8s a = *(const v8s*)(Wqkv_bf + (size_t)(r0 + l15) * 192 + ks * 32 + quad * 8);
#pragma unroll
      for (int nt = 0; nt < 4; nt++) {
        v8s bb = *(const v8s*)(XP + (nt * 16 + l15) * 200 + ks * 32 + quad * 8);
        acc[nt] = __builtin_amdgcn_mfma_f32_16x16x32_bf16(a, bb, acc[nt], 0, 0, 0);
      }
    }
    int R = r0 + quad * 4;
#pragma unroll
    for (int nt = 0; nt < 4; nt++) {
      int hw = nt * 16 + l15;
      if (R < 192) {
        short4 s;
        s.x = f2bf(acc[nt][0] * SCALE); s.y = f2bf(acc[nt][1] * SCALE);
        s.z = f2bf(acc[nt][2] * SCALE); s.w = f2bf(acc[nt][3] * SCALE);
        *(short4*)(Qb + obase + (size_t)hw * 192 + R) = s;
      } else if (R < 384) {
        short4 s;
        s.x = f2bf(acc[nt][0]); s.y = f2bf(acc[nt][1]);
        s.z = f2bf(acc[nt][2]); s.w = f2bf(acc[nt][3]);
        *(short4*)(Kb + obase + (size_t)hw * 192 + (R - 192)) = s;
      } else {
#pragma unroll
        for (int r = 0; r < 4; r++)
          Vtb[obase + (size_t)(R - 384 + r) * 64 + hw] = f2bf(acc[nt][r]);
      }
    }
  }
}

// ---- main fused kernel: one block per (i,b), 512 threads (8 waves).
// GEMM split: wave (wc=w&3, wh=w>>2): 48-ch slice x 32-hw half (3 cti x 2 nt tiles).
// Attention split: wave (qt=w&3, hg=w>>2): 16 q-rows x 3 heads.
// Weights streamed from L2 each use (no register preload) -> VGPR<=128 -> 2 blocks/CU, 4 waves/SIMD.
__global__ __launch_bounds__(512, 4) void fused_all(
    const float* __restrict__ x,
    const short* __restrict__ Qb, const short* __restrict__ Kb,
    const short* __restrict__ Vtb,
    const short* __restrict__ Wproj_bf, const short* __restrict__ W1_bf,
    const short* __restrict__ W2_bf,
    const float* __restrict__ bproj, const float* __restrict__ gamma,
    const float* __restrict__ beta, const float* __restrict__ b1,
    const float* __restrict__ b2,
    float* __restrict__ out) {
  __shared__ short SP[64 * 200];     // Xi staging / o / y1n / h: [hw][ch]
  __shared__ short Pl[8][16 * 72];   // per-wave P: [q][hw_k]
  __shared__ float LNp[64][4][2];    // LN partials: [hw][wc][s1,s2]

  // XCD swizzle: 6 i-blocks sharing b land on one XCD (shared K/V in its L2)
  int bid = blockIdx.x;
  int xcd = bid & 7, idx6 = bid >> 3;
  int bq = idx6 / TT;
  int b = xcd * 16 + bq, i = idx6 - bq * TT;

  int tid = threadIdx.x, w = tid >> 6, lane = tid & 63;
  int l15 = lane & 15, quad = lane >> 4;
  int wc = w & 3, wh = w >> 2;
  int cb = wc * 48;
  const v4f vzero = {0.f, 0.f, 0.f, 0.f};

  // ---- stage Xi (x.view reinterpretation rows) as bf16 into SP ----
  const float* xi = x + (size_t)(i * NB + b) * 64 * DIM;
  for (int c = tid; c < 64 * 24; c += 512) {
    int row = c / 24, col8 = (c - (c / 24) * 24) * 8;
    const float* xs = xi + row * DIM + col8;
    v8s r8;
#pragma unroll
    for (int jj = 0; jj < 8; jj++) r8[jj] = f2bf(xs[jj]);
    *(v8s*)(SP + row * 200 + col8) = r8;
  }
  __syncthreads();

  // ---- y1x = Wproj[:,192:384] . Xi^T  (j-invariant half of G1, computed once) ----
  v4f y1x[3][2];
#pragma unroll
  for (int cti = 0; cti < 3; cti++)
#pragma unroll
    for (int nt = 0; nt < 2; nt++) y1x[cti][nt] = vzero;
#pragma unroll
  for (int ks = 0; ks < 6; ks++) {
    v8s bxi[2];
#pragma unroll
    for (int nt = 0; nt < 2; nt++)
      bxi[nt] = *(const v8s*)(SP + (wh * 32 + nt * 16 + l15) * 200 + ks * 32 + quad * 8);
#pragma unroll
    for (int cti = 0; cti < 3; cti++) {
      v8s a = *(const v8s*)(Wproj_bf + (size_t)(cb + cti * 16 + l15) * 384 + 192 + ks * 32 + quad * 8);
#pragma unroll
      for (int nt = 0; nt < 2; nt++)
        y1x[cti][nt] = __builtin_amdgcn_mfma_f32_16x16x32_bf16(a, bxi[nt], y1x[cti][nt], 0, 0, 0);
    }
  }

  v4f acc[3][2];
#pragma unroll
  for (int cti = 0; cti < 3; cti++)
#pragma unroll
    for (int nt = 0; nt < 2; nt++) acc[cti][nt] = vzero;

  const short* Qi = Qb + (size_t)(b * TT + i) * 64 * DIM;

  for (int j = 0; j < TT; j++) {
    __syncthreads();               // prior SP reads (Xi / G3 h) done before o overwrites
    const short* Kj = Kb + (size_t)(b * TT + j) * 64 * DIM;
    const short* Vj = Vtb + (size_t)(b * TT + j) * 64 * DIM;

    // ---- attention: wave (qt, hg) handles q-rows qt*16..+15, heads hg*3..+2 ----
#pragma unroll
    for (int hh = 0; hh < 3; hh++) {
      int h = wh * 3 + hh;         // hg == wh
      v8s qa = *(const v8s*)(Qi + (size_t)(wc * 16 + l15) * 192 + h * 32 + quad * 8);  // qt == wc
      v4f S[4];
#pragma unroll
      for (int cta = 0; cta < 4; cta++) {
        v8s akq = *(const v8s*)(Kj + (size_t)(cta * 16 + l15) * 192 + h * 32 + quad * 8);
        S[cta] = __builtin_amdgcn_mfma_f32_16x16x32_bf16(akq, qa, vzero, 0, 0, 0);
      }
      float mx = -1e30f;
#pragma unroll
      for (int cta = 0; cta < 4; cta++)
#pragma unroll
        for (int r = 0; r < 4; r++) mx = fmaxf(mx, S[cta][r]);
      mx = fmaxf(mx, __shfl_xor(mx, 16, 64));
      mx = fmaxf(mx, __shfl_xor(mx, 32, 64));
      float sum = 0.f;
#pragma unroll
      for (int cta = 0; cta < 4; cta++)
#pragma unroll
        for (int r = 0; r < 4; r++) {
          float e = __expf(S[cta][r] - mx);
          S[cta][r] = e; sum += e;
        }
      sum += __shfl_xor(sum, 16, 64);
      sum += __shfl_xor(sum, 32, 64);
      float inv = 1.0f / sum;
#pragma unroll
      for (int cta = 0; cta < 4; cta++) {
        short4 s;
        s.x = f2bf(S[cta][0] * inv); s.y = f2bf(S[cta][1] * inv);
        s.z = f2bf(S[cta][2] * inv); s.w = f2bf(S[cta][3] * inv);
        *(short4*)(&Pl[w][l15 * 72 + cta * 16 + quad * 4]) = s;
      }
      fence();
      v8s bp0 = *(const v8s*)(&Pl[w][l15 * 72 + quad * 8]);
      v8s bp1 = *(const v8s*)(&Pl[w][l15 * 72 + 32 + quad * 8]);
#pragma unroll
      for (int ct2 = 0; ct2 < 2; ct2++) {
        v8s av0 = *(const v8s*)(Vj + (size_t)(h * 32 + ct2 * 16 + l15) * 64 + quad * 8);
        v8s av1 = *(const v8s*)(Vj + (size_t)(h * 32 + ct2 * 16 + l15) * 64 + 32 + quad * 8);
        v4f o = __builtin_amdgcn_mfma_f32_16x16x32_bf16(av0, bp0, vzero, 0, 0, 0);
        o = __builtin_amdgcn_mfma_f32_16x16x32_bf16(av1, bp1, o, 0, 0, 0);
        short4 s;
        s.x = f2bf(o[0]); s.y = f2bf(o[1]); s.z = f2bf(o[2]); s.w = f2bf(o[3]);
        *(short4*)(&SP[(wc * 16 + l15) * 200 + h * 32 + ct2 * 16 + quad * 4]) = s;
      }
      fence();
    }
    __syncthreads();               // o complete

    // ---- G1: y1 = y1x + Wproj[:,0:192] . o^T ----
    v4f y1[3][2];
#pragma unroll
    for (int cti = 0; cti < 3; cti++)
#pragma unroll
      for (int nt = 0; nt < 2; nt++) y1[cti][nt] = y1x[cti][nt];
#pragma unroll
    for (int ks = 0; ks < 6; ks++) {
      v8s bo[2];
#pragma unroll
      for (int nt = 0; nt < 2; nt++)
        bo[nt] = *(const v8s*)(SP + (wh * 32 + nt * 16 + l15) * 200 + ks * 32 + quad * 8);
#pragma unroll
      for (int cti = 0; cti < 3; cti++) {
        v8s a = *(const v8s*)(Wproj_bf + (size_t)(cb + cti * 16 + l15) * 384 + ks * 32 + quad * 8);
#pragma unroll
        for (int nt = 0; nt < 2; nt++)
          y1[cti][nt] = __builtin_amdgcn_mfma_f32_16x16x32_bf16(a, bo[nt], y1[cti][nt], 0, 0, 0);
      }
    }
    // + bproj; LN partials
#pragma unroll
    for (int cti = 0; cti < 3; cti++) {
      float4 bp4 = *(const float4*)(bproj + cb + cti * 16 + quad * 4);
#pragma unroll
      for (int nt = 0; nt < 2; nt++) {
        y1[cti][nt][0] += bp4.x; y1[cti][nt][1] += bp4.y;
        y1[cti][nt][2] += bp4.z; y1[cti][nt][3] += bp4.w;
      }
    }
#pragma unroll
    for (int nt = 0; nt < 2; nt++) {
      float s1 = 0.f, s2 = 0.f;
#pragma unroll
      for (int cti = 0; cti < 3; cti++)
#pragma unroll
        for (int r = 0; r < 4; r++) { float v = y1[cti][nt][r]; s1 += v; s2 += v * v; }
      s1 += __shfl_xor(s1, 16, 64); s2 += __shfl_xor(s2, 16, 64);
      s1 += __shfl_xor(s1, 32, 64); s2 += __shfl_xor(s2, 32, 64);
      if (quad == 0) {
        LNp[wh * 32 + nt * 16 + l15][wc][0] = s1;
        LNp[wh * 32 + nt * 16 + l15][wc][1] = s2;
      }
    }
    __syncthreads();               // partials visible; G1 strip reads done
    float mu[2], rs[2];
#pragma unroll
    for (int nt = 0; nt < 2; nt++) {
      int row = wh * 32 + nt * 16 + l15;
      float s1 = 0.f, s2 = 0.f;
#pragma unroll
      for (int ww = 0; ww < 4; ww++) { s1 += LNp[row][ww][0]; s2 += LNp[row][ww][1]; }
      float m = s1 * (1.0f / 192.0f);
      mu[nt] = m; rs[nt] = rsqrtf(s2 * (1.0f / 192.0f) - m * m + 1e-5f);
    }
#pragma unroll
    for (int cti = 0; cti < 3; cti++) {
      float4 g4 = *(const float4*)(gamma + cb + cti * 16 + quad * 4);
      float4 be4 = *(const float4*)(beta + cb + cti * 16 + quad * 4);
#pragma unroll
      for (int nt = 0; nt < 2; nt++) {
        short4 s;
        s.x = f2bf((y1[cti][nt][0] - mu[nt]) * rs[nt] * g4.x + be4.x);
        s.y = f2bf((y1[cti][nt][1] - mu[nt]) * rs[nt] * g4.y + be4.y);
        s.z = f2bf((y1[cti][nt][2] - mu[nt]) * rs[nt] * g4.z + be4.z);
        s.w = f2bf((y1[cti][nt][3] - mu[nt]) * rs[nt] * g4.w + be4.w);
        *(short4*)(&SP[(wh * 32 + nt * 16 + l15) * 200 + cb + cti * 16 + quad * 4]) = s;
      }
    }
    __syncthreads();               // y1n ready

    // ---- G2: y2 = W1 . y1n^T ----
    v4f y2[3][2];
#pragma unroll
    for (int cti = 0; cti < 3; cti++)
#pragma unroll
      for (int nt = 0; nt < 2; nt++) y2[cti][nt] = vzero;
#pragma unroll
    for (int ks = 0; ks < 6; ks++) {
      v8s bh[2];
#pragma unroll
      for (int nt = 0; nt < 2; nt++)
        bh[nt] = *(const v8s*)(SP + (wh * 32 + nt * 16 + l15) * 200 + ks * 32 + quad * 8);
#pragma unroll
      for (int cti = 0; cti < 3; cti++) {
        v8s a = *(const v8s*)(W1_bf + (size_t)(cb + cti * 16 + l15) * 192 + ks * 32 + quad * 8);
#pragma unroll
        for (int nt = 0; nt < 2; nt++)
          y2[cti][nt] = __builtin_amdgcn_mfma_f32_16x16x32_bf16(a, bh[nt], y2[cti][nt], 0, 0, 0);
      }
    }
    __syncthreads();               // G2 strip reads done before h overwrite
#pragma unroll
    for (int cti = 0; cti < 3; cti++) {
      float4 b14 = *(const float4*)(b1 + cb + cti * 16 + quad * 4);
#pragma unroll
      for (int nt = 0; nt < 2; nt++) {
        float vv[4] = {y2[cti][nt][0] + b14.x, y2[cti][nt][1] + b14.y,
                       y2[cti][nt][2] + b14.z, y2[cti][nt][3] + b14.w};
        short sv[4];
#pragma unroll
        for (int r = 0; r < 4; r++) {
          float v = vv[r];
          float t = 0.79788456080286536f * (v + 0.044715f * v * v * v);
          float e = __expf(2.0f * t);
          float th = 1.0f - 2.0f / (e + 1.0f);
          sv[r] = f2bf(0.5f * v * (1.0f + th));
        }
        short4 s;
        s.x = sv[0]; s.y = sv[1]; s.z = sv[2]; s.w = sv[3];
        *(short4*)(&SP[(wh * 32 + nt * 16 + l15) * 200 + cb + cti * 16 + quad * 4]) = s;
      }
    }
    __syncthreads();               // h ready

    // ---- G3: acc += W2 . h^T ----
#pragma unroll
    for (int ks = 0; ks < 6; ks++) {
      v8s bh[2];
#pragma unroll
      for (int nt = 0; nt < 2; nt++)
        bh[nt] = *(const v8s*)(SP + (wh * 32 + nt * 16 + l15) * 200 + ks * 32 + quad * 8);
#pragma unroll
      for (int cti = 0; cti < 3; cti++) {
        v8s a = *(const v8s*)(W2_bf + (size_t)(cb + cti * 16 + l15) * 192 + ks * 32 + quad * 8);
#pragma unroll
        for (int nt = 0; nt < 2; nt++)
          acc[cti][nt] = __builtin_amdgcn_mfma_f32_16x16x32_bf16(a, bh[nt], acc[cti][nt], 0, 0, 0);
      }
    }
  }

  // ---- epilogue: out = [x | x + acc/6 + b2] ----
#pragma unroll
  for (int cti = 0; cti < 3; cti++) {
    int cc0 = cb + cti * 16 + quad * 4;
    float4 b24 = *(const float4*)(b2 + cc0);
#pragma unroll
    for (int nt = 0; nt < 2; nt++) {
      int hw = wh * 32 + nt * 16 + l15;
      size_t nrow = (size_t)b * 384 + (size_t)i * 64 + hw;
      float4 xv = *(const float4*)(x + nrow * DIM + cc0);
      float4 o4;
      o4.x = xv.x + acc[cti][nt][0] * (1.0f / 6.0f) + b24.x;
      o4.y = xv.y + acc[cti][nt][1] * (1.0f / 6.0f) + b24.y;
      o4.z = xv.z + acc[cti][nt][2] * (1.0f / 6.0f) + b24.z;
      o4.w = xv.w + acc[cti][nt][3] * (1.0f / 6.0f) + b24.w;
      *(float4*)(out + nrow * 384 + 192 + cc0) = o4;
    }
  }
  // x-half bit-exact copy
  for (int c = tid; c < 64 * 48; c += 512) {
    int row = c / 48, col4 = (c - (c / 48) * 48) * 4;
    size_t nrow = (size_t)b * 384 + (size_t)i * 64 + row;
    *(float4*)(out + nrow * 384 + col4) = *(const float4*)(x + nrow * DIM + col4);
  }
}

extern "C" void kernel_launch(void* const* d_in, const int* in_sizes, int n_in,
                              void* d_out, int out_size, void* d_ws, size_t ws_size,
                              hipStream_t stream) {
  (void)in_sizes; (void)n_in; (void)out_size; (void)ws_size;
  const float* x     = (const float*)d_in[0];
  const float* Wqkv  = (const float*)d_in[1];
  const float* Wproj = (const float*)d_in[2];
  const float* bproj = (const float*)d_in[3];
  const float* gamma = (const float*)d_in[4];
  const float* beta  = (const float*)d_in[5];
  const float* W1    = (const float*)d_in[6];
  const float* b1    = (const float*)d_in[7];
  const float* W2    = (const float*)d_in[8];
  const float* b2    = (const float*)d_in[9];
  float* out = (float*)d_out;

  // workspace layout (bytes): 516096 weights + 49152 pos + 3x18874368 QKV = 57.2 MB
  short* Wqkv_bf  = (short*)d_ws;                 // 576*192
  short* Wproj_bf = Wqkv_bf + 110592;             // 192*384
  short* W1_bf    = Wproj_bf + 73728;             // 192*192
  short* W2_bf    = W1_bf + 36864;                // 192*192
  float* pos_f    = (float*)(W2_bf + 36864);      // 64*192 f32
  short* Qb       = (short*)(pos_f + 12288);      // [b][t][hw][ch]
  short* Kb       = Qb + 9437184;                 // [b][t][hw][ch]
  short* Vtb      = Kb + 9437184;                 // [b][t][ch][hw]

  cvt_kernel<<<dim3(108), dim3(256), 0, stream>>>(Wqkv, Wqkv_bf, 110592 / 4);
  cvt_kernel<<<dim3(72), dim3(256), 0, stream>>>(Wproj, Wproj_bf, 73728 / 4);
  cvt_kernel<<<dim3(36), dim3(256), 0, stream>>>(W1, W1_bf, 36864 / 4);
  cvt_kernel<<<dim3(36), dim3(256), 0, stream>>>(W2, W2_bf, 36864 / 4);
  pos_kernel<<<dim3(48), dim3(256), 0, stream>>>(pos_f);
  qkv_kernel<<<dim3(TT * NB), dim3(256), 0, stream>>>(x, pos_f, Wqkv_bf, Qb, Kb, Vtb);
  fused_all<<<dim3(TT * NB), dim3(512), 0, stream>>>(
      x, Qb, Kb, Vtb, Wproj_bf, W1_bf, W2_bf, bproj, gamma, beta, b1, b2, out);
}